// Round 1
// baseline (327.131 us; speedup 1.0000x reference)
//
#include <hip/hip_runtime.h>
#include <math.h>

#define BATCH 2
#define NPTS  2048
#define CIN   64
#define COUT  64
#define NCELL 9

static __device__ __forceinline__ float cell_ox(int k) {
    return ((k / 3) - 1) * 0.05f;
}
static __device__ __forceinline__ float cell_oy(int k) {
    return ((k % 3) - 1) * 0.05f;
}

// knorm = 315 / (64*pi*0.1^9), computed in double then truncated like the ref
#define KNORM 1.5666851e9f
#define R2 0.01f

// ---------------------------------------------------------------------------
// Kernel 1: dcoef[b,c,j] = data[b,c,j] / (invmass[b,j] * density[b,j])
// ---------------------------------------------------------------------------
__global__ __launch_bounds__(256) void dcoef_kernel(
    const float* __restrict__ locs, const float* __restrict__ data,
    const float* __restrict__ density, float* __restrict__ dcoef)
{
    int e = blockIdx.x * 256 + threadIdx.x;        // 0 .. B*CIN*N-1
    int j = e & (NPTS - 1);
    int bc = e >> 11;                               // b*CIN + c
    int b = bc >> 6;
    float im = locs[(b * NPTS + j) * 3 + 2];
    float de = density[b * NPTS + j];
    dcoef[e] = data[e] / (im * de);
}

// ---------------------------------------------------------------------------
// Kernel 2: field[b,k,c,i] = sum_j w_k(i,j) * dcoef[b,c,j]
// Block = 256 threads = 4 waves; each wave owns one i, lane = channel c.
// Per 64-j chunk: phase 1 (thread = (i_local = wave, jj = lane)) computes the
// 9 w values + ballot mask of active jj; phase 2 iterates only active jj.
// ---------------------------------------------------------------------------
__global__ __launch_bounds__(256) void field_kernel(
    const float* __restrict__ locs, const float* __restrict__ dcoef,
    float* __restrict__ field)
{
    __shared__ float  dcs[64 * 65];          // dcs[jj][c], padded stride 65
    __shared__ float4 wls[4 * 64 * 3];       // wls[(il*64+jj)*3 + {0,1,2}]

    const int tid  = threadIdx.x;
    const int lane = tid & 63;
    const int wid  = tid >> 6;
    const int blk  = blockIdx.x;             // 0 .. B*N/4-1
    const int b    = blk >> 9;               // 512 i-groups per batch
    const int i    = (blk & 511) * 4 + wid;

    const float xi = locs[(b * NPTS + i) * 3 + 0];
    const float yi = locs[(b * NPTS + i) * 3 + 1];

    float f[NCELL];
#pragma unroll
    for (int k = 0; k < NCELL; k++) f[k] = 0.0f;

    for (int jc = 0; jc < NPTS; jc += 64) {
        // ---- stage dcoef chunk: dcs[jj][c] = dcoef[b,c,jc+jj] (coalesced) --
#pragma unroll
        for (int c4 = 0; c4 < 64; c4 += 4) {
            int c = c4 + wid;
            dcs[lane * 65 + c] = dcoef[(b * CIN + c) * NPTS + jc + lane];
        }

        // ---- phase 1: w for (i_local = wid, jj = lane) ---------------------
        int j = jc + lane;
        float xj = locs[(b * NPTS + j) * 3 + 0];
        float yj = locs[(b * NPTS + j) * 3 + 1];
        float dx = xi - xj;
        float dy = yi - yj;

        float wv[NCELL];
        bool any = false;
#pragma unroll
        for (int k = 0; k < NCELL; k++) {
            float ax = dx + cell_ox(k);
            float ay = dy + cell_oy(k);
            float d2 = fmaf(ax, ax, ay * ay);
            float t = R2 - d2;
            bool hit = t > 0.0f;
            wv[k] = hit ? t * t * t * KNORM : 0.0f;
            any |= hit;
        }
        if (any) {
            float4* wp = &wls[(wid * 64 + lane) * 3];
            wp[0] = make_float4(wv[0], wv[1], wv[2], wv[3]);
            wp[1] = make_float4(wv[4], wv[5], wv[6], wv[7]);
            wp[2] = make_float4(wv[8], 0.0f, 0.0f, 0.0f);
        }
        unsigned long long m = __ballot(any);
        __syncthreads();

        // ---- phase 2: lane = channel, iterate active jj only ---------------
        while (m) {
            int jj = __builtin_ctzll(m);
            m &= m - 1;
            float dc = dcs[jj * 65 + lane];
            const float4* wq = &wls[(wid * 64 + jj) * 3];
            float4 w0 = wq[0];
            float4 w1 = wq[1];
            float4 w2 = wq[2];
            f[0] = fmaf(w0.x, dc, f[0]);
            f[1] = fmaf(w0.y, dc, f[1]);
            f[2] = fmaf(w0.z, dc, f[2]);
            f[3] = fmaf(w0.w, dc, f[3]);
            f[4] = fmaf(w1.x, dc, f[4]);
            f[5] = fmaf(w1.y, dc, f[5]);
            f[6] = fmaf(w1.z, dc, f[6]);
            f[7] = fmaf(w1.w, dc, f[7]);
            f[8] = fmaf(w2.x, dc, f[8]);
        }
        __syncthreads();
    }

    // field[b][k][c][i], i contiguous for kernel-3 coalescing
#pragma unroll
    for (int k = 0; k < NCELL; k++)
        field[((b * NCELL + k) * CIN + lane) * NPTS + i] = f[k];
}

// ---------------------------------------------------------------------------
// Kernel 3: out[b,o,i] = bias[o] + sum_{k,c} weight[o,c,k] * field[b,k,c,i]
// Grid (B*N/64, 8), 64 threads; lane = i offset (coalesced field/out access),
// weight/bias loads are wave-uniform -> scalar loads.
// ---------------------------------------------------------------------------
__global__ __launch_bounds__(64) void out_kernel(
    const float* __restrict__ field, const float* __restrict__ weight,
    const float* __restrict__ bias, float* __restrict__ out)
{
    const int lane = threadIdx.x;
    const int tile = blockIdx.x;             // b*32 + itile
    const int og   = blockIdx.y;             // o-group of 8
    const int b    = tile >> 5;
    const int i0   = (tile & 31) * 64;

    float acc[8];
#pragma unroll
    for (int m = 0; m < 8; m++) acc[m] = bias[og * 8 + m];

    for (int k = 0; k < NCELL; k++) {
#pragma unroll 4
        for (int c = 0; c < CIN; c++) {
            float fv = field[((b * NCELL + k) * CIN + c) * NPTS + i0 + lane];
#pragma unroll
            for (int m = 0; m < 8; m++)
                acc[m] = fmaf(weight[(og * 8 + m) * (CIN * NCELL) + c * NCELL + k],
                              fv, acc[m]);
        }
    }
#pragma unroll
    for (int m = 0; m < 8; m++)
        out[(b * COUT + og * 8 + m) * NPTS + i0 + lane] = acc[m];
}

extern "C" void kernel_launch(void* const* d_in, const int* in_sizes, int n_in,
                              void* d_out, int out_size, void* d_ws, size_t ws_size,
                              hipStream_t stream)
{
    const float* locs    = (const float*)d_in[0];   // (B, N, 3)
    const float* data    = (const float*)d_in[1];   // (B, CIN, N)
    const float* density = (const float*)d_in[2];   // (B, N)
    const float* weight  = (const float*)d_in[3];   // (COUT, CIN, 9)
    const float* bias    = (const float*)d_in[4];   // (COUT,)
    float* out = (float*)d_out;                     // (B, COUT, N)

    float* dcoef = (float*)d_ws;                    // B*CIN*N floats (1 MB)
    float* field = dcoef + BATCH * CIN * NPTS;      // B*9*CIN*N floats (9.4 MB)

    dcoef_kernel<<<BATCH * CIN * NPTS / 256, 256, 0, stream>>>(
        locs, data, density, dcoef);
    field_kernel<<<BATCH * NPTS / 4, 256, 0, stream>>>(
        locs, dcoef, field);
    out_kernel<<<dim3(BATCH * NPTS / 64, 8), 64, 0, stream>>>(
        field, weight, bias, out);
}

// Round 2
// 148.517 us; speedup vs baseline: 2.2026x; 2.2026x over previous
//
#include <hip/hip_runtime.h>
#include <stdint.h>

#define BATCH 2
#define NPTS  2048
#define CIN   64
#define COUT  64
#define NCELL 9

// knorm = 315 / (64*pi*0.1^9)
#define KNORM 1.5666851e9f
#define R2 0.01f

static __device__ __forceinline__ float cell_ox(int k) { return ((k / 3) - 1) * 0.05f; }
static __device__ __forceinline__ float cell_oy(int k) { return ((k % 3) - 1) * 0.05f; }

typedef __attribute__((address_space(3))) uint8_t        lds_t;
typedef const __attribute__((address_space(1))) uint8_t  glb_t;

// ---------------------------------------------------------------------------
// Workspace layout (floats):
//   dcoefT [B][N][64]        262144   (j-major so 64j x 64c tiles are contiguous)
//   posT   [B][N] float2       8192
//   W2T    [9][64c][64o]      36864
//   field  [B][9][64c][N]   2359296
// ---------------------------------------------------------------------------

// Prep: dcoefT = transpose(data * 1/(invmass*density)), posT, W2T.
__global__ __launch_bounds__(256) void prep_kernel(
    const float* __restrict__ locs, const float* __restrict__ data,
    const float* __restrict__ density, const float* __restrict__ weight,
    float* __restrict__ dcoefT, float2* __restrict__ posT, float* __restrict__ W2T)
{
    const int tid = threadIdx.x, lane = tid & 63, wid = tid >> 6;
    const int g = blockIdx.x;
    if (g < BATCH * (NPTS / 64)) {
        __shared__ float tile[64 * 65];
        const int b = g >> 5, j0 = (g & 31) * 64;
        const int j = j0 + lane;
        float im = locs[(b * NPTS + j) * 3 + 2];
        float de = density[b * NPTS + j];
        float coef = 1.0f / (im * de);
        if (wid == 0)
            posT[b * NPTS + j] =
                make_float2(locs[(b * NPTS + j) * 3 + 0], locs[(b * NPTS + j) * 3 + 1]);
#pragma unroll
        for (int it = 0; it < 16; it++) {
            int c = it * 4 + wid;
            tile[c * 65 + lane] = data[(b * CIN + c) * NPTS + j] * coef;
        }
        __syncthreads();
#pragma unroll
        for (int it = 0; it < 16; it++) {
            int jr = it * 4 + wid;
            dcoefT[(b * NPTS + j0 + jr) * 64 + lane] = tile[lane * 65 + jr];
        }
    } else {
        const int k = g - BATCH * (NPTS / 64);          // 0..8
        for (int e = tid; e < 64 * 64; e += 256) {
            int c = e >> 6, o = e & 63;
            W2T[(k * 64 + c) * 64 + o] = weight[(o * CIN + c) * NCELL + k];
        }
    }
}

// ---------------------------------------------------------------------------
// Field: field[b,k,c,i] = sum_j w_k(i,j) * dcoef[b,c,j]
// Block = 4 waves, one i per wave, lane = channel in phase 2.
// dcoefT chunk staged via global_load_lds (contiguous, width=16).
// ---------------------------------------------------------------------------
__global__ __launch_bounds__(256) void field_kernel(
    const float2* __restrict__ posT, const float* __restrict__ dcoefT,
    float* __restrict__ field)
{
    __shared__ float  dcs[64 * 64];          // dcs[jj][c], contiguous for load_lds
    __shared__ float4 wls[4 * 64 * 3];       // wls[(wave*64+jj)*3 + q]

    const int tid  = threadIdx.x;
    const int lane = tid & 63;
    const int wid  = tid >> 6;
    const int blk  = blockIdx.x;
    const int b    = blk >> 9;
    const int i    = (blk & 511) * 4 + wid;

    const float2 pi = posT[b * NPTS + i];

    float f[NCELL];
#pragma unroll
    for (int k = 0; k < NCELL; k++) f[k] = 0.0f;

    for (int jc = 0; jc < NPTS; jc += 64) {
        // ---- async stage: dcoefT[b][jc..jc+63][0..63] -> dcs (16 KB) -------
        const float* src = dcoefT + (b * NPTS + jc) * 64;
#pragma unroll
        for (int s = 0; s < 4; s++) {
            int seg = wid * 4 + s;                       // 16 x 1KB segments
            __builtin_amdgcn_global_load_lds(
                (glb_t*)(src + seg * 256 + lane * 4),
                (lds_t*)(&dcs[seg * 256]), 16, 0, 0);
        }

        // ---- phase 1: w for (i_local = wid, jj = lane) ---------------------
        float2 pj = posT[b * NPTS + jc + lane];
        float dx = pi.x - pj.x;
        float dy = pi.y - pj.y;

        float wv[NCELL];
        bool any = false;
#pragma unroll
        for (int k = 0; k < NCELL; k++) {
            float ax = dx + cell_ox(k);
            float ay = dy + cell_oy(k);
            float d2 = fmaf(ax, ax, ay * ay);
            float t = R2 - d2;
            bool hit = t > 0.0f;
            wv[k] = hit ? t * t * t * KNORM : 0.0f;
            any |= hit;
        }
        if (any) {
            float4* wp = &wls[(wid * 64 + lane) * 3];
            wp[0] = make_float4(wv[0], wv[1], wv[2], wv[3]);
            wp[1] = make_float4(wv[4], wv[5], wv[6], wv[7]);
            wp[2] = make_float4(wv[8], 0.0f, 0.0f, 0.0f);
        }
        unsigned long long m = __ballot(any);
        __syncthreads();   // drains load_lds (vmcnt) + wls visible

        // ---- phase 2: lane = channel, iterate active jj only ---------------
        while (m) {
            int jj = __builtin_ctzll(m);
            m &= m - 1;
            float dc = dcs[jj * 64 + lane];
            const float4* wq = &wls[(wid * 64 + jj) * 3];
            float4 w0 = wq[0];
            float4 w1 = wq[1];
            float4 w2 = wq[2];
            f[0] = fmaf(w0.x, dc, f[0]);
            f[1] = fmaf(w0.y, dc, f[1]);
            f[2] = fmaf(w0.z, dc, f[2]);
            f[3] = fmaf(w0.w, dc, f[3]);
            f[4] = fmaf(w1.x, dc, f[4]);
            f[5] = fmaf(w1.y, dc, f[5]);
            f[6] = fmaf(w1.z, dc, f[6]);
            f[7] = fmaf(w1.w, dc, f[7]);
            f[8] = fmaf(w2.x, dc, f[8]);
        }
        __syncthreads();   // dcs/wls consumed before next chunk's staging
    }

#pragma unroll
    for (int k = 0; k < NCELL; k++)
        field[((b * NCELL + k) * CIN + lane) * NPTS + i] = f[k];
}

// ---------------------------------------------------------------------------
// Out: LDS-tiled GEMM. Block computes 64o x 16i over full K=576.
// Grid = B * 128 = 256 blocks x 256 threads. Bias folded into store.
// ---------------------------------------------------------------------------
__global__ __launch_bounds__(256) void out_kernel(
    const float* __restrict__ field, const float* __restrict__ W2T,
    const float* __restrict__ bias, float* __restrict__ out)
{
    __shared__ float Wt[64 * 64];    // [kk][o]
    __shared__ float Ft[64 * 16];    // [kk][ii]

    const int tid = threadIdx.x;
    const int o   = tid & 63;
    const int ig  = tid >> 6;
    const int b   = blockIdx.x >> 7;
    const int i0  = (blockIdx.x & 127) * 16;

    float acc0 = 0.0f, acc1 = 0.0f, acc2 = 0.0f, acc3 = 0.0f;

    for (int k = 0; k < NCELL; k++) {
        __syncthreads();
        // stage weight slice (contiguous 16 KB)
        const float4* ws = (const float4*)(W2T + k * 4096);
        float4*       wd = (float4*)Wt;
#pragma unroll
        for (int s = 0; s < 4; s++) wd[s * 256 + tid] = ws[s * 256 + tid];
        // stage field tile: 64 rows (c) x 16 i
        {
            int c = tid >> 2, q = tid & 3;
            float4 fv = *(const float4*)(field + ((b * NCELL + k) * CIN + c) * NPTS + i0 + q * 4);
            *(float4*)(Ft + c * 16 + q * 4) = fv;
        }
        __syncthreads();
#pragma unroll 8
        for (int kk = 0; kk < 64; kk++) {
            float  w  = Wt[kk * 64 + o];
            float4 fv = *(const float4*)(Ft + kk * 16 + ig * 4);
            acc0 = fmaf(w, fv.x, acc0);
            acc1 = fmaf(w, fv.y, acc1);
            acc2 = fmaf(w, fv.z, acc2);
            acc3 = fmaf(w, fv.w, acc3);
        }
    }

    float bv = bias[o];
    float4 r = make_float4(bv + acc0, bv + acc1, bv + acc2, bv + acc3);
    *(float4*)(out + (b * COUT + o) * NPTS + i0 + ig * 4) = r;
}

extern "C" void kernel_launch(void* const* d_in, const int* in_sizes, int n_in,
                              void* d_out, int out_size, void* d_ws, size_t ws_size,
                              hipStream_t stream)
{
    const float* locs    = (const float*)d_in[0];   // (B, N, 3)
    const float* data    = (const float*)d_in[1];   // (B, CIN, N)
    const float* density = (const float*)d_in[2];   // (B, N)
    const float* weight  = (const float*)d_in[3];   // (COUT, CIN, 9)
    const float* bias    = (const float*)d_in[4];   // (COUT,)
    float* out = (float*)d_out;                     // (B, COUT, N)

    float*  dcoefT = (float*)d_ws;                           // 262144
    float2* posT   = (float2*)(dcoefT + BATCH * NPTS * 64);  // 8192 floats
    float*  W2T    = (float*)(posT + BATCH * NPTS);          // 36864
    float*  field  = W2T + NCELL * 64 * 64;                  // 2359296

    prep_kernel<<<BATCH * (NPTS / 64) + NCELL, 256, 0, stream>>>(
        locs, data, density, weight, dcoefT, posT, W2T);
    field_kernel<<<BATCH * NPTS / 4, 256, 0, stream>>>(posT, dcoefT, field);
    out_kernel<<<BATCH * 128, 256, 0, stream>>>(field, W2T, bias, out);
}

// Round 3
// 146.447 us; speedup vs baseline: 2.2338x; 1.0141x over previous
//
#include <hip/hip_runtime.h>
#include <stdint.h>

#define BATCH 2
#define NPTS  2048
#define CIN   64
#define COUT  64
#define NCELL 9

// knorm = 315 / (64*pi*0.1^9)
#define KNORM 1.5666851e9f
#define R2 0.01f

static __device__ __forceinline__ float rdlane(float v, int l) {
    return __int_as_float(__builtin_amdgcn_readlane(__float_as_int(v), l));
}

// ---------------------------------------------------------------------------
// Workspace (floats):
//   dcoefT [B][N][64]      262144
//   posT   [B][N] float2     8192
//   W2T    [9][64c][64o]    36864
//   field  [B][9][64c][N] 2359296
//   part   [3][B][64o][N]  786432     (split-K partials)
// ---------------------------------------------------------------------------

__global__ __launch_bounds__(256) void prep_kernel(
    const float* __restrict__ locs, const float* __restrict__ data,
    const float* __restrict__ density, const float* __restrict__ weight,
    float* __restrict__ dcoefT, float2* __restrict__ posT, float* __restrict__ W2T)
{
    const int tid = threadIdx.x, lane = tid & 63, wid = tid >> 6;
    const int g = blockIdx.x;
    if (g < BATCH * (NPTS / 64)) {
        __shared__ float tile[64 * 65];
        const int b = g >> 5, j0 = (g & 31) * 64;
        const int j = j0 + lane;
        float im = locs[(b * NPTS + j) * 3 + 2];
        float de = density[b * NPTS + j];
        float coef = 1.0f / (im * de);
        if (wid == 0)
            posT[b * NPTS + j] =
                make_float2(locs[(b * NPTS + j) * 3 + 0], locs[(b * NPTS + j) * 3 + 1]);
#pragma unroll
        for (int it = 0; it < 16; it++) {
            int c = it * 4 + wid;
            tile[c * 65 + lane] = data[(b * CIN + c) * NPTS + j] * coef;
        }
        __syncthreads();
#pragma unroll
        for (int it = 0; it < 16; it++) {
            int jr = it * 4 + wid;
            dcoefT[(b * NPTS + j0 + jr) * 64 + lane] = tile[lane * 65 + jr];
        }
    } else {
        const int k = g - BATCH * (NPTS / 64);
        for (int e = tid; e < 64 * 64; e += 256) {
            int c = e >> 6, o = e & 63;
            W2T[(k * 64 + c) * 64 + o] = weight[(o * CIN + c) * NCELL + k];
        }
    }
}

// ---------------------------------------------------------------------------
// Field: one i per wave, lane = channel. No LDS, no barriers.
// Phase 1 (lane = jj): 9-cell kernel weights + ballot of "any cell active".
// Phase 2: ctz loop over active jj; w broadcast via v_readlane (VALU, not LDS);
// dcoef row read straight from L2 (coalesced 256B), one-iteration prefetch.
// ---------------------------------------------------------------------------
__global__ __launch_bounds__(256) void field_kernel(
    const float2* __restrict__ posT, const float* __restrict__ dcoefT,
    float* __restrict__ field)
{
    const int tid  = threadIdx.x;
    const int lane = tid & 63;
    const int wid  = tid >> 6;
    const int gi   = blockIdx.x * 4 + wid;     // global i (B*N of them)
    const int b    = gi >> 11;
    const int i    = gi & (NPTS - 1);

    const float2 pi = posT[gi];
    const float* dcb = dcoefT + (size_t)b * NPTS * 64;

    float f[NCELL];
#pragma unroll
    for (int k = 0; k < NCELL; k++) f[k] = 0.0f;

    for (int jc = 0; jc < NPTS; jc += 64) {
        float2 pj = posT[b * NPTS + jc + lane];
        float dx = pi.x - pj.x;
        float dy = pi.y - pj.y;

        float ax0 = dx - 0.05f, ax1 = dx, ax2 = dx + 0.05f;
        float ay0 = dy - 0.05f, ay1 = dy, ay2 = dy + 0.05f;
        float ty0 = fmaf(-ay0, ay0, R2);
        float ty1 = fmaf(-ay1, ay1, R2);
        float ty2 = fmaf(-ay2, ay2, R2);

        float t[NCELL];
        t[0] = fmaf(-ax0, ax0, ty0);
        t[1] = fmaf(-ax0, ax0, ty1);
        t[2] = fmaf(-ax0, ax0, ty2);
        t[3] = fmaf(-ax1, ax1, ty0);
        t[4] = fmaf(-ax1, ax1, ty1);
        t[5] = fmaf(-ax1, ax1, ty2);
        t[6] = fmaf(-ax2, ax2, ty0);
        t[7] = fmaf(-ax2, ax2, ty1);
        t[8] = fmaf(-ax2, ax2, ty2);

        float wv[NCELL];
        float tmax = t[0];
#pragma unroll
        for (int k = 0; k < NCELL; k++) {
            float mt = fmaxf(t[k], 0.0f);
            wv[k] = mt * mt * (mt * KNORM);   // == max(r2-d2,0)^3 * knorm
            if (k) tmax = fmaxf(tmax, t[k]);
        }

        unsigned long long m = __ballot(tmax > 0.0f);
        const float* dcj = dcb + jc * 64;

        if (m) {
            int jj = __builtin_ctzll(m); m &= m - 1;
            float dc = dcj[jj * 64 + lane];
            while (m) {
                int jj2 = __builtin_ctzll(m); m &= m - 1;
                float dc2 = dcj[jj2 * 64 + lane];   // prefetch next pair
#pragma unroll
                for (int k = 0; k < NCELL; k++)
                    f[k] = fmaf(rdlane(wv[k], jj), dc, f[k]);
                jj = jj2; dc = dc2;
            }
#pragma unroll
            for (int k = 0; k < NCELL; k++)
                f[k] = fmaf(rdlane(wv[k], jj), dc, f[k]);
        }
    }

#pragma unroll
    for (int k = 0; k < NCELL; k++)
        field[((b * NCELL + k) * CIN + lane) * NPTS + i] = f[k];
}

// ---------------------------------------------------------------------------
// Out GEMM, split-K by cell-group (3 cells each). Block = 64o x 64i tile,
// thread = 4o x 4i (16 FMA per 2 x ds_read_b128). Grid (B*N/64, 3).
// ---------------------------------------------------------------------------
__global__ __launch_bounds__(256) void out_gemm(
    const float* __restrict__ field, const float* __restrict__ W2T,
    float* __restrict__ part)
{
    __shared__ float Wt[64 * 64];   // [c][o]
    __shared__ float Ft[64 * 64];   // [c][i]

    const int tid = threadIdx.x;
    const int o4  = (tid & 15) * 4;
    const int i4  = (tid >> 4) * 4;
    const int bx  = blockIdx.x;
    const int b   = bx >> 5;
    const int i0  = (bx & 31) * 64;
    const int kg  = blockIdx.y;

    float acc[16];
#pragma unroll
    for (int e = 0; e < 16; e++) acc[e] = 0.0f;

    const int cs = tid >> 2, qs = tid & 3;     // staging row / quarter

    for (int ks = 0; ks < 3; ks++) {
        const int k = kg * 3 + ks;
        __syncthreads();
        {
            const float4* ws = (const float4*)(W2T + k * 4096);
            float4*       wd = (float4*)Wt;
#pragma unroll
            for (int s = 0; s < 4; s++) wd[s * 256 + tid] = ws[s * 256 + tid];

            const float* fr = field + ((b * NCELL + k) * CIN + cs) * NPTS + i0;
#pragma unroll
            for (int s = 0; s < 4; s++)
                *(float4*)(Ft + cs * 64 + qs * 16 + s * 4) =
                    *(const float4*)(fr + qs * 16 + s * 4);
        }
        __syncthreads();

#pragma unroll 8
        for (int kk = 0; kk < 64; kk++) {
            float4 w4 = *(const float4*)(Wt + kk * 64 + o4);
            float4 f4 = *(const float4*)(Ft + kk * 64 + i4);
            acc[0]  = fmaf(w4.x, f4.x, acc[0]);
            acc[1]  = fmaf(w4.x, f4.y, acc[1]);
            acc[2]  = fmaf(w4.x, f4.z, acc[2]);
            acc[3]  = fmaf(w4.x, f4.w, acc[3]);
            acc[4]  = fmaf(w4.y, f4.x, acc[4]);
            acc[5]  = fmaf(w4.y, f4.y, acc[5]);
            acc[6]  = fmaf(w4.y, f4.z, acc[6]);
            acc[7]  = fmaf(w4.y, f4.w, acc[7]);
            acc[8]  = fmaf(w4.z, f4.x, acc[8]);
            acc[9]  = fmaf(w4.z, f4.y, acc[9]);
            acc[10] = fmaf(w4.z, f4.z, acc[10]);
            acc[11] = fmaf(w4.z, f4.w, acc[11]);
            acc[12] = fmaf(w4.w, f4.x, acc[12]);
            acc[13] = fmaf(w4.w, f4.y, acc[13]);
            acc[14] = fmaf(w4.w, f4.z, acc[14]);
            acc[15] = fmaf(w4.w, f4.w, acc[15]);
        }
    }

    float* pd = part + ((size_t)kg * BATCH + b) * COUT * NPTS;
#pragma unroll
    for (int mo = 0; mo < 4; mo++) {
        float4 st = make_float4(acc[mo * 4 + 0], acc[mo * 4 + 1],
                                acc[mo * 4 + 2], acc[mo * 4 + 3]);
        *(float4*)(pd + (o4 + mo) * NPTS + i0 + i4) = st;
    }
}

// out = bias + p0 + p1 + p2
__global__ __launch_bounds__(256) void reduce_out(
    const float* __restrict__ part, const float* __restrict__ bias,
    float* __restrict__ out)
{
    const int idx = blockIdx.x * 256 + threadIdx.x;   // 65536 float4 groups
    const int e4  = idx * 4;
    const int o   = (e4 >> 11) & 63;
    const float4 p0 = *(const float4*)(part + e4);
    const float4 p1 = *(const float4*)(part + BATCH * COUT * NPTS + e4);
    const float4 p2 = *(const float4*)(part + 2 * BATCH * COUT * NPTS + e4);
    float bv = bias[o];
    float4 r = make_float4(bv + p0.x + p1.x + p2.x, bv + p0.y + p1.y + p2.y,
                           bv + p0.z + p1.z + p2.z, bv + p0.w + p1.w + p2.w);
    *(float4*)(out + e4) = r;
}

extern "C" void kernel_launch(void* const* d_in, const int* in_sizes, int n_in,
                              void* d_out, int out_size, void* d_ws, size_t ws_size,
                              hipStream_t stream)
{
    const float* locs    = (const float*)d_in[0];
    const float* data    = (const float*)d_in[1];
    const float* density = (const float*)d_in[2];
    const float* weight  = (const float*)d_in[3];
    const float* bias    = (const float*)d_in[4];
    float* out = (float*)d_out;

    float*  dcoefT = (float*)d_ws;                            // 262144
    float2* posT   = (float2*)(dcoefT + BATCH * NPTS * 64);   // 8192 floats
    float*  W2T    = (float*)(posT + BATCH * NPTS);           // 36864
    float*  field  = W2T + NCELL * 64 * 64;                   // 2359296
    float*  part   = field + BATCH * NCELL * CIN * NPTS;      // 786432

    prep_kernel<<<BATCH * (NPTS / 64) + NCELL, 256, 0, stream>>>(
        locs, data, density, weight, dcoefT, posT, W2T);
    field_kernel<<<BATCH * NPTS / 4, 256, 0, stream>>>(posT, dcoefT, field);
    out_gemm<<<dim3(BATCH * (NPTS / 64), 3), 256, 0, stream>>>(field, W2T, part);
    reduce_out<<<BATCH * COUT * NPTS / 1024, 256, 0, stream>>>(part, bias, out);
}